// Round 9
// baseline (98.697 us; speedup 1.0000x reference)
//
#include <hip/hip_runtime.h>
#include <hip/hip_bf16.h>
#include <stdint.h>

// Problem constants (fixed by reference)
#define LQ   2048
#define NH   16
#define DD   128
#define NB   2
#define QBLK 64           // q-rows per strip (4 waves x 16)
#define KBLK 64           // K/V tile rows
#define NQT2 (LQ/QBLK)    // 32 strips per head; block pairs qt2 <-> 31-qt2
#define ROWSTR (NH*DD)    // 2048 floats between consecutive seq rows
#define KTILE (KBLK*132)  // 8448 shorts per K tile buffer
#define VTILE (32*256)    // 8192 shorts per V tile buffer

typedef float f32x4 __attribute__((ext_vector_type(4)));
typedef short s16x4 __attribute__((ext_vector_type(4)));
typedef short s16x8 __attribute__((ext_vector_type(8)));

// scalar cast -> compiler packs into v_cvt_pk_bf16_f32 (m240)
__device__ __forceinline__ short f2bf(float f) {
  union { __hip_bfloat16 h; short s; } u;
  u.h = __float2bfloat16(f);
  return u.s;
}

__device__ __forceinline__ s16x4 cvt4(f32x4 x) {
  s16x4 r; r[0] = f2bf(x[0]); r[1] = f2bf(x[1]); r[2] = f2bf(x[2]); r[3] = f2bf(x[3]);
  return r;
}

__device__ __forceinline__ uint32_t lds_u32(const void* p) {
  return (uint32_t)(uint64_t)p;
}

// hardware transpose read (verified config): addr = subtile_base + 8*lane over a
// contiguous 128B-aligned [16][16] bf16 subtile -> lane gets col l15, rows 4*lhi+j
__device__ __forceinline__ s16x4 tr16(uint32_t addr) {
  s16x4 d;
  asm volatile("ds_read_b64_tr_b16 %0, %1" : "=v"(d) : "v"(addr) : "memory");
  return d;
}

// 256 threads stage a 64x128 f32 tile pair (K row-major padded, V subtiled)
struct Stage { f32x4 k[8]; f32x4 v[8]; };

__device__ __forceinline__ Stage load_tile(const float* __restrict__ Kg,
                                           const float* __restrict__ Vg,
                                           int s0, int tid) {
  Stage st;
  const int rk = tid >> 5;          // 0..7
  const int c4 = tid & 31;
#pragma unroll
  for (int j = 0; j < 8; ++j)
    st.k[j] = *(const f32x4*)(Kg + (size_t)(s0 + rk + 8 * j) * ROWSTR + 4 * c4);
#pragma unroll
  for (int p = 0; p < 8; ++p) {
    const int g = tid + 256 * p;                // 0..2047, bijective map
    const int rv = (g & 3) | ((g >> 7) << 2);   // 0..63
    const int cv = (g >> 2) & 31;
    st.v[p] = *(const f32x4*)(Vg + (size_t)(s0 + rv) * ROWSTR + 4 * cv);
  }
  return st;
}

__device__ __forceinline__ void write_tile(short* Kb, short* Vb,
                                           const Stage& st, int tid) {
  const int rk = tid >> 5;
  const int c4 = tid & 31;
  // K row-major padded 132 (measured conflict-free)
#pragma unroll
  for (int j = 0; j < 8; ++j)
    *(s16x4*)&Kb[(rk + 8 * j) * 132 + 4 * c4] = cvt4(st.k[j]);
#pragma unroll
  for (int p = 0; p < 8; ++p) {
    const int g = tid + 256 * p;
    const int rv = (g & 3) | ((g >> 7) << 2);
    const int cv = (g >> 2) & 31;
    const int sub = (rv >> 4) * 8 + (cv >> 2);   // s_grp*8 + d_blk, 0..31
    *(s16x4*)&Vb[sub * 256 + (rv & 15) * 16 + 4 * (cv & 3)] = cvt4(st.v[p]);
  }
}

__global__ __launch_bounds__(256, 2) void qattn_fwd(
    const float* __restrict__ keys, const float* __restrict__ values,
    float* __restrict__ out)
{
  __shared__ short SM[2 * KTILE + 2 * VTILE];       // 66,560 B -> 2 blocks/CU

  const int tid  = threadIdx.x;
  const int wid  = tid >> 6;      // 0..3 waves
  const int lane = tid & 63;
  const int l15  = lane & 15;
  const int lhi  = lane >> 4;     // 0..3

  // 512 blocks, ALL with identical work (33 tiles) -> placement-invariant
  // balance. Same-head blocks share an XCD (wg = bh mod 32, 32 % 8 == 0).
  const int wg = blockIdx.x;
  const int bh = wg & 31;
  const int z  = wg >> 5;               // 0..15
  const int b  = bh >> 4;
  const int h  = bh & 15;

  const float* Kg = keys   + ((size_t)b * LQ * ROWSTR) + (size_t)h * DD;
  const float* Vg = values + ((size_t)b * LQ * ROWSTR) + (size_t)h * DD;
  float*       Og = out    + ((size_t)b * LQ * ROWSTR) + (size_t)h * DD;

  // logits * (0.5/sqrt(128)) * log2(e); folded into Q fragments.
  // quantum_score cancels in softmax (uniform shift).
  const float CS = 0.5f * 0.08838834764831845f * 1.4426950408889634f;

  // two strips: qt2 and 31-qt2 -> nt sums to 33 for every block
  for (int sp = 0; sp < 2; ++sp) {
    const int qt2 = sp ? (NQT2 - 1 - z) : z;
    const int q0  = qt2 * QBLK;
    const int nt  = qt2 + 1;            // 64-row tiles covering s <= q0+63

    // ---- Q fragments (Q := values rows), CS pre-folded, f32 -> bf16 regs ----
    const int qg = q0 + wid * 16 + l15; // this lane's q-row
    const float* Qrow = Vg + (size_t)qg * ROWSTR;
    s16x8 qf[4];
#pragma unroll
    for (int c = 0; c < 4; ++c) {
      f32x4 lo = *(const f32x4*)(Qrow + 32 * c + 4 * lhi);
      f32x4 hi = *(const f32x4*)(Qrow + 32 * c + 16 + 4 * lhi);
      lo *= CS; hi *= CS;
      qf[c] = __builtin_shufflevector(cvt4(lo), cvt4(hi), 0, 1, 2, 3, 4, 5, 6, 7);
    }

    f32x4 o[8];
#pragma unroll
    for (int i = 0; i < 8; ++i) o[i] = f32x4{0.f, 0.f, 0.f, 0.f};
    float m  = -1e30f;   // running max (exp2-logit units), keyed by q = l15
    float ll = 0.0f;

    // ---- prologue: stage tile 0 into buf 0 (prior strip's readers are past
    //      the loop-end barrier; epilogue touches only global memory) ----
    {
      Stage st = load_tile(Kg, Vg, 0, tid);
      write_tile(SM, SM + 2 * KTILE, st, tid);
    }
    __syncthreads();

    for (int t = 0; t < nt; ++t) {
      const int cur = t & 1;
      const int s0  = t * KBLK;

      // issue next tile's global loads early (latency hides under compute)
      Stage st;
      const bool more = (t + 1) < nt;
      if (more) st = load_tile(Kg, Vg, (t + 1) * KBLK, tid);

      {
        const short* Kb = SM + cur * KTILE;
        const short* Vb = SM + 2 * KTILE + cur * VTILE;

        // ---- QK^T swapped: sT[sb] = K_sb · Q^T -> S^T[s][q] ----
        f32x4 sT[4];
#pragma unroll
        for (int sb = 0; sb < 4; ++sb) sT[sb] = f32x4{0.f, 0.f, 0.f, 0.f};
        __builtin_amdgcn_s_setprio(1);
#pragma unroll
        for (int c = 0; c < 4; ++c) {
#pragma unroll
          for (int sb = 0; sb < 4; ++sb) {
            s16x4 a  = *(const s16x4*)&Kb[(sb * 16 + l15) * 132 + 32 * c + 4 * lhi];
            s16x4 bb = *(const s16x4*)&Kb[(sb * 16 + l15) * 132 + 32 * c + 16 + 4 * lhi];
            s16x8 kf = __builtin_shufflevector(a, bb, 0, 1, 2, 3, 4, 5, 6, 7);
            sT[sb] = __builtin_amdgcn_mfma_f32_16x16x32_bf16(kf, qf[c], sT[sb], 0, 0, 0);
          }
        }
        __builtin_amdgcn_s_setprio(0);

        // ---- online softmax: lane owns q=l15, s = s0 + sb*16 + 4*lhi + r ----
        if (s0 + KBLK - 1 > qg) {            // diagonal tile: causal mask
#pragma unroll
          for (int sb = 0; sb < 4; ++sb)
#pragma unroll
            for (int r = 0; r < 4; ++r)
              if (s0 + sb * 16 + 4 * lhi + r > qg) sT[sb][r] = -1e30f;
        }
        float tm = sT[0][0];
#pragma unroll
        for (int sb = 0; sb < 4; ++sb)
#pragma unroll
          for (int r = 0; r < 4; ++r) tm = fmaxf(tm, sT[sb][r]);
        tm = fmaxf(tm, __shfl_xor(tm, 16));
        tm = fmaxf(tm, __shfl_xor(tm, 32));

        // defer-max (T13): only rescale when max grew past THR=8 (exp2 units)
        if (!__all(tm - m <= 8.0f)) {
          const float mn = fmaxf(m, tm);
          const float alpha = exp2f(m - mn);
          m = mn;
          float ar[4];
#pragma unroll
          for (int r = 0; r < 4; ++r) ar[r] = __shfl(alpha, 4 * lhi + r);
#pragma unroll
          for (int df = 0; df < 8; ++df)
#pragma unroll
            for (int r = 0; r < 4; ++r) o[df][r] *= ar[r];
          ll *= alpha;
        }
        float rs = 0.f;
        s16x8 pf0, pf1;
#pragma unroll
        for (int sb = 0; sb < 2; ++sb)
#pragma unroll
          for (int r = 0; r < 4; ++r) {
            float p = exp2f(sT[sb][r] - m);
            rs += p;
            pf0[sb * 4 + r] = f2bf(p);
          }
#pragma unroll
        for (int sb = 0; sb < 2; ++sb)
#pragma unroll
          for (int r = 0; r < 4; ++r) {
            float p = exp2f(sT[2 + sb][r] - m);
            rs += p;
            pf1[sb * 4 + r] = f2bf(p);
          }
        rs += __shfl_xor(rs, 16);
        rs += __shfl_xor(rs, 32);
        ll += rs;

        // ---- PV via hardware transpose reads, two 32-row k-slots ----
        const uint32_t vbase = lds_u32(Vb) + 8u * (uint32_t)lane;
#pragma unroll
        for (int ks = 0; ks < 2; ++ks) {
          s16x4 vlo[8], vhi[8];
#pragma unroll
          for (int df = 0; df < 8; ++df) {
            vlo[df] = tr16(vbase + 512u * (uint32_t)(16 * ks + df));
            vhi[df] = tr16(vbase + 512u * (uint32_t)(16 * ks + 8 + df));
          }
          asm volatile("s_waitcnt lgkmcnt(0)" ::: "memory");
          __builtin_amdgcn_sched_barrier(0);
          const s16x8 pf = ks ? pf1 : pf0;
          __builtin_amdgcn_s_setprio(1);
#pragma unroll
          for (int df = 0; df < 8; ++df) {
            s16x8 vf = __builtin_shufflevector(vlo[df], vhi[df], 0, 1, 2, 3, 4, 5, 6, 7);
            o[df] = __builtin_amdgcn_mfma_f32_16x16x32_bf16(pf, vf, o[df], 0, 0, 0);
          }
          __builtin_amdgcn_s_setprio(0);
        }
      }

      // write next tile into the other buffer (compiler inserts vmcnt wait)
      if (more) write_tile(SM + (cur ^ 1) * KTILE,
                           SM + 2 * KTILE + (cur ^ 1) * VTILE, st, tid);
      __syncthreads();                   // single barrier per tile
    }

    // ---- epilogue: O /= l, store f32 (global only; no LDS hazard) ----
    const float linv = 1.0f / ll;
#pragma unroll
    for (int r = 0; r < 4; ++r) {
      const float lr = __shfl(linv, 4 * lhi + r);
      float* orow = Og + (size_t)(q0 + wid * 16 + 4 * lhi + r) * ROWSTR;
#pragma unroll
      for (int df = 0; df < 8; ++df)
        orow[df * 16 + l15] = o[df][r] * lr;
    }
  }
}

extern "C" void kernel_launch(void* const* d_in, const int* in_sizes, int n_in,
                              void* d_out, int out_size, void* d_ws, size_t ws_size,
                              hipStream_t stream) {
  // inputs: 0=queries (dead), 1=keys, 2=values, 3=q_params (dead: softmax shift)
  const float* keys   = (const float*)d_in[1];
  const float* values = (const float*)d_in[2];
  float*       out    = (float*)d_out;
  dim3 grid(NB * NH * (NQT2 / 2));   // 512 blocks, equal work -> 2/CU overlap
  dim3 block(256);
  hipLaunchKernelGGL(qattn_fwd, grid, block, 0, stream, keys, values, out);
}